// Round 5
// baseline (250.850 us; speedup 1.0000x reference)
//
#include <hip/hip_runtime.h>

#define LSEQ 2048
#define DIM 512
#define NH 8
#define HS 64

typedef __attribute__((ext_vector_type(8))) short short8;
typedef __attribute__((ext_vector_type(4))) float f32x4;

__device__ inline unsigned short f2bf(float f) {
  union { float f; unsigned u; } a; a.f = f;
  unsigned r = a.u + 0x7FFFu + ((a.u >> 16) & 1u);
  return (unsigned short)(r >> 16);
}
__device__ inline float bf2f(unsigned short h) {
  union { unsigned u; float f; } a; a.u = ((unsigned)h) << 16;
  return a.f;
}

__device__ inline f32x4 mfma_bf16(short8 a, short8 b, f32x4 c) {
  return __builtin_amdgcn_mfma_f32_16x16x32_bf16(a, b, c, 0, 0, 0);
}

__device__ inline short8 ld8(const unsigned short* p) {
  return *reinterpret_cast<const short8*>(p);
}

// ---------------- fused fp32 -> bf16 weight/Er convert ----------------
__global__ __launch_bounds__(256) void cvt_all_kernel(
    const float* __restrict__ wq, const float* __restrict__ wk,
    const float* __restrict__ wv, const float* __restrict__ wo,
    const float* __restrict__ Er,
    unsigned short* __restrict__ wqb, unsigned short* __restrict__ wkb,
    unsigned short* __restrict__ wvb, unsigned short* __restrict__ wob,
    unsigned short* __restrict__ erb) {
  int b = blockIdx.x;
  const float* src; unsigned short* dst; int off;
  if (b < 256)       { src = wq; dst = wqb; off = b; }
  else if (b < 512)  { src = wk; dst = wkb; off = b - 256; }
  else if (b < 768)  { src = wv; dst = wvb; off = b - 512; }
  else if (b < 1024) { src = wo; dst = wob; off = b - 768; }
  else               { src = Er; dst = erb; off = b - 1024; }
  int i = (off * 256 + threadIdx.x) * 4;
  float4 v = *reinterpret_cast<const float4*>(src + i);
  unsigned lo = (unsigned)f2bf(v.x) | ((unsigned)f2bf(v.y) << 16);
  unsigned hi = (unsigned)f2bf(v.z) | ((unsigned)f2bf(v.w) << 16);
  uint2 pk; pk.x = lo; pk.y = hi;
  *reinterpret_cast<uint2*>(dst + i) = pk;
}

// ---------------- LayerNorm: one wave per row, no barriers ----------------
__global__ __launch_bounds__(256) void ln_kernel(const float* __restrict__ x,
    const float* __restrict__ g, const float* __restrict__ bta,
    unsigned short* __restrict__ hn) {
  int lane = threadIdx.x & 63, w = threadIdx.x >> 6;
  int row = blockIdx.x * 4 + w;
  const float4* xr = reinterpret_cast<const float4*>(x + (size_t)row * DIM);
  float4 a = xr[2 * lane], c = xr[2 * lane + 1];
  float s = a.x + a.y + a.z + a.w + c.x + c.y + c.z + c.w;
  float sq = a.x * a.x + a.y * a.y + a.z * a.z + a.w * a.w +
             c.x * c.x + c.y * c.y + c.z * c.z + c.w * c.w;
#pragma unroll
  for (int off = 1; off < 64; off <<= 1) {
    s += __shfl_xor(s, off);
    sq += __shfl_xor(sq, off);
  }
  float mu = s * (1.f / DIM);
  float var = sq * (1.f / DIM) - mu * mu;
  float rstd = rsqrtf(var + 1e-5f);
  float4 g0 = reinterpret_cast<const float4*>(g)[2 * lane];
  float4 g1 = reinterpret_cast<const float4*>(g)[2 * lane + 1];
  float4 b0 = reinterpret_cast<const float4*>(bta)[2 * lane];
  float4 b1 = reinterpret_cast<const float4*>(bta)[2 * lane + 1];
  uint4 o;
  o.x = (unsigned)f2bf((a.x - mu) * rstd * g0.x + b0.x) |
        ((unsigned)f2bf((a.y - mu) * rstd * g0.y + b0.y) << 16);
  o.y = (unsigned)f2bf((a.z - mu) * rstd * g0.z + b0.z) |
        ((unsigned)f2bf((a.w - mu) * rstd * g0.w + b0.w) << 16);
  o.z = (unsigned)f2bf((c.x - mu) * rstd * g1.x + b1.x) |
        ((unsigned)f2bf((c.y - mu) * rstd * g1.y + b1.y) << 16);
  o.w = (unsigned)f2bf((c.z - mu) * rstd * g1.z + b1.z) |
        ((unsigned)f2bf((c.w - mu) * rstd * g1.w + b1.w) << 16);
  reinterpret_cast<uint4*>(hn)[(size_t)row * 64 + lane] = o;
}

// ---------------- QKV projections: 32x64 tile per wave ----------------
__global__ __launch_bounds__(256) void qkv_kernel(const unsigned short* __restrict__ hn,
    const unsigned short* __restrict__ wqb, const unsigned short* __restrict__ wkb,
    const unsigned short* __restrict__ wvb,
    const float* __restrict__ bq, const float* __restrict__ bk, const float* __restrict__ bv,
    unsigned short* __restrict__ qo, unsigned short* __restrict__ ko,
    unsigned short* __restrict__ vT) {
  int lane = threadIdx.x & 63, widx = threadIdx.x >> 6;
  int col = lane & 15, grp = lane >> 4;
  int wgid = blockIdx.x * 4 + widx;  // 0..3071
  int mat = wgid >> 10;
  int rem = wgid & 1023;
  int m0 = (rem >> 3) * 32;
  int n0 = (rem & 7) * 64;
  const unsigned short* W = (mat == 0) ? wqb : (mat == 1) ? wkb : wvb;
  const float* bias = (mat == 0) ? bq : (mat == 1) ? bk : bv;
  f32x4 acc[2][4];
#pragma unroll
  for (int i = 0; i < 2; ++i)
#pragma unroll
    for (int j = 0; j < 4; ++j) acc[i][j] = (f32x4){0.f, 0.f, 0.f, 0.f};
  for (int k0 = 0; k0 < DIM; k0 += 32) {
    short8 af0 = ld8(hn + (size_t)(m0 + col) * DIM + k0 + 8 * grp);
    short8 af1 = ld8(hn + (size_t)(m0 + 16 + col) * DIM + k0 + 8 * grp);
#pragma unroll
    for (int nt = 0; nt < 4; ++nt) {
      short8 bf = ld8(W + (size_t)(n0 + nt * 16 + col) * DIM + k0 + 8 * grp);
      acc[0][nt] = mfma_bf16(af0, bf, acc[0][nt]);
      acc[1][nt] = mfma_bf16(af1, bf, acc[1][nt]);
    }
  }
#pragma unroll
  for (int nt = 0; nt < 4; ++nt) {
    int n = n0 + nt * 16 + col;   // feature
    int hh = n >> 6, d = n & 63;
    float bsv = bias[n];
#pragma unroll
    for (int mi = 0; mi < 2; ++mi) {
#pragma unroll
      for (int r = 0; r < 4; ++r) {
        int m = m0 + 16 * mi + 4 * grp + r;   // token
        float val = acc[mi][nt][r] + bsv;
        int b = m >> 11, l = m & (LSEQ - 1);
        unsigned short hv = f2bf(val);
        if (mat == 2)
          vT[((size_t)(b * NH + hh) * HS + d) * LSEQ + l] = hv;
        else {
          unsigned short* dst = (mat == 0) ? qo : ko;
          dst[((size_t)(b * NH + hh) * LSEQ + l) * HS + d] = hv;
        }
      }
    }
  }
}

// ---------------- single-pass flash attention with skewed rel bias ----------
// one wave per (bh, 16-row q-tile): 2048 waves in 512 blocks, ALL resident.
// Inner loop over 64-key tiles; loads issued up-front each iter; no fences;
// exact defer-rescale online softmax; writes attT directly (no merge pass).
__global__ __launch_bounds__(256) void attn_kernel(const unsigned short* __restrict__ q,
    const unsigned short* __restrict__ k, const unsigned short* __restrict__ vT,
    const unsigned short* __restrict__ erb, unsigned short* __restrict__ attT) {
  __shared__ float Uall[4][80 * 18];
  int lane = threadIdx.x & 63, widx = threadIdx.x >> 6;
  int mcol = lane & 15, grp = lane >> 4;
  float* U = Uall[widx];
  // XCD pinning: blocks of (bh, bh+8) land on xcd = bh&7 -> ~1.8MB/XCD L2 set
  int bid = blockIdx.x;            // 0..511
  int xcd = bid & 7, j = bid >> 3; // j 0..63
  int bh = xcd + 8 * (j >> 5);
  int tile = ((j & 31) << 2) | widx;  // 0..127
  int qi0 = tile << 4;
  int h = bh & 7, b = bh >> 3;

  const unsigned short* Qb = q + (size_t)bh * LSEQ * HS;
  const unsigned short* Kb = k + (size_t)bh * LSEQ * HS;
  const unsigned short* Vb = vT + (size_t)bh * HS * LSEQ;
  const unsigned short* Eb = erb + (size_t)h * LSEQ * HS;

  short8 qf0 = ld8(Qb + (size_t)(qi0 + mcol) * HS + 8 * grp);
  short8 qf1 = ld8(Qb + (size_t)(qi0 + mcol) * HS + 32 + 8 * grp);
  f32x4 o[4];
#pragma unroll
  for (int i = 0; i < 4; ++i) o[i] = (f32x4){0.f, 0.f, 0.f, 0.f};
  float mrun = -3e38f, lsum = 0.f;
  int nkb = (qi0 + 79) >> 6;

  for (int kb = 0; kb < nkb; ++kb) {
    int kj0 = kb << 6;
    int e0 = 2032 - qi0 + kj0;
    // ---- issue all global loads up front (26 in flight) ----
    short8 ef[10];
#pragma unroll
    for (int jt = 0; jt < 5; ++jt) {
      int er = min(e0 + 16 * jt + mcol, 2047);  // clamped rows feed masked cells
      ef[2 * jt]     = ld8(Eb + (size_t)er * HS + 8 * grp);
      ef[2 * jt + 1] = ld8(Eb + (size_t)er * HS + 32 + 8 * grp);
    }
    short8 kf[8];
#pragma unroll
    for (int t = 0; t < 4; ++t) {
      kf[2 * t]     = ld8(Kb + (size_t)(kj0 + 16 * t + mcol) * HS + 8 * grp);
      kf[2 * t + 1] = ld8(Kb + (size_t)(kj0 + 16 * t + mcol) * HS + 32 + 8 * grp);
    }
    short8 vf[8];
#pragma unroll
    for (int s2 = 0; s2 < 2; ++s2)
#pragma unroll
      for (int dt = 0; dt < 4; ++dt)
        vf[s2 * 4 + dt] = ld8(Vb + (size_t)(dt * 16 + mcol) * LSEQ + kj0 + 32 * s2 + 8 * grp);
    // ---- rel-bias band U[j][m], j in [0,80) ----
#pragma unroll
    for (int jt = 0; jt < 5; ++jt) {
      f32x4 uu = (f32x4){0.f, 0.f, 0.f, 0.f};
      uu = mfma_bf16(ef[2 * jt], qf0, uu);
      uu = mfma_bf16(ef[2 * jt + 1], qf1, uu);
#pragma unroll
      for (int r = 0; r < 4; ++r)
        U[(16 * jt + 4 * grp + r) * 18 + mcol] = uu[r];
    }
    // ---- scores S^T ----
    f32x4 st[4];
#pragma unroll
    for (int t = 0; t < 4; ++t) {
      f32x4 a = (f32x4){0.f, 0.f, 0.f, 0.f};
      a = mfma_bf16(kf[2 * t], qf0, a);
      a = mfma_bf16(kf[2 * t + 1], qf1, a);
      st[t] = a;
    }
    // ---- logits + causal mask + skew gather rel[n][m] = U[n-m+15][m] ----
    float lt[4][4];
    float pmax = -3e38f;
#pragma unroll
    for (int t = 0; t < 4; ++t) {
#pragma unroll
      for (int r = 0; r < 4; ++r) {
        int n = 16 * t + 4 * grp + r;
        float val = st[t][r] * 0.125f + U[(n - mcol + 15) * 18 + mcol];
        if (kj0 + n > qi0 + mcol) val = -3e38f;
        lt[t][r] = val;
        pmax = fmaxf(pmax, val);
      }
    }
    pmax = fmaxf(pmax, __shfl_xor(pmax, 16));
    pmax = fmaxf(pmax, __shfl_xor(pmax, 32));
    // exact defer-rescale: only rescale when some row's max grew
    if (!__all(pmax <= mrun)) {
      float mnew = fmaxf(mrun, pmax);
      float alpha = __expf(mrun - mnew);
      lsum *= alpha;
#pragma unroll
      for (int i2 = 0; i2 < 4; ++i2) o[i2] *= alpha;
      mrun = mnew;
    }
    float psum = 0.f;
#pragma unroll
    for (int t = 0; t < 4; ++t) {
#pragma unroll
      for (int r = 0; r < 4; ++r) {
        lt[t][r] = __expf(lt[t][r] - mrun);
        psum += lt[t][r];
      }
    }
    psum += __shfl_xor(psum, 16);
    psum += __shfl_xor(psum, 32);
    lsum += psum;
    // ---- pack P and redistribute to B-fragment via shuffles ----
    unsigned w0[4], w1[4];
#pragma unroll
    for (int t = 0; t < 4; ++t) {
      w0[t] = (unsigned)f2bf(lt[t][0]) | ((unsigned)f2bf(lt[t][1]) << 16);
      w1[t] = (unsigned)f2bf(lt[t][2]) | ((unsigned)f2bf(lt[t][3]) << 16);
    }
    int srcA = mcol | ((grp & 1) << 5);
    int srcB = srcA + 16;
    bool hi = (grp >= 2);
#pragma unroll
    for (int s2 = 0; s2 < 2; ++s2) {
      unsigned y0a = (unsigned)__shfl((int)w0[2 * s2], srcA);
      unsigned y0b = (unsigned)__shfl((int)w0[2 * s2 + 1], srcA);
      unsigned y1a = (unsigned)__shfl((int)w1[2 * s2], srcA);
      unsigned y1b = (unsigned)__shfl((int)w1[2 * s2 + 1], srcA);
      unsigned y2a = (unsigned)__shfl((int)w0[2 * s2], srcB);
      unsigned y2b = (unsigned)__shfl((int)w0[2 * s2 + 1], srcB);
      unsigned y3a = (unsigned)__shfl((int)w1[2 * s2], srcB);
      unsigned y3b = (unsigned)__shfl((int)w1[2 * s2 + 1], srcB);
      union { unsigned u4[4]; short8 s8; } pu;
      pu.u4[0] = hi ? y0b : y0a;
      pu.u4[1] = hi ? y1b : y1a;
      pu.u4[2] = hi ? y2b : y2a;
      pu.u4[3] = hi ? y3b : y3a;
#pragma unroll
      for (int dt = 0; dt < 4; ++dt)
        o[dt] = mfma_bf16(vf[s2 * 4 + dt], pu.s8, o[dt]);
    }
  }
  // ---- finalize + direct attT write ----
  float inv = 1.f / lsum;
  size_t rowbase = ((size_t)(b * LSEQ) + qi0 + mcol) * DIM + h * HS;
#pragma unroll
  for (int dt = 0; dt < 4; ++dt) {
    unsigned p0 = (unsigned)f2bf(o[dt][0] * inv) | ((unsigned)f2bf(o[dt][1] * inv) << 16);
    unsigned p1 = (unsigned)f2bf(o[dt][2] * inv) | ((unsigned)f2bf(o[dt][3] * inv) << 16);
    int d0 = dt * 16 + 4 * grp;
    *reinterpret_cast<unsigned*>(attT + rowbase + d0)     = p0;
    *reinterpret_cast<unsigned*>(attT + rowbase + d0 + 2) = p1;
  }
}

// ---------------- output projection: 32x64 tile per wave -> fp32 ----------
__global__ __launch_bounds__(256) void out_kernel(const unsigned short* __restrict__ attT,
    const unsigned short* __restrict__ wob, const float* __restrict__ bo,
    float* __restrict__ out) {
  int lane = threadIdx.x & 63, widx = threadIdx.x >> 6;
  int col = lane & 15, grp = lane >> 4;
  int wgid = blockIdx.x * 4 + widx;  // 0..1023
  int m0 = (wgid >> 3) * 32;
  int n0 = (wgid & 7) * 64;
  f32x4 acc[2][4];
#pragma unroll
  for (int i = 0; i < 2; ++i)
#pragma unroll
    for (int j = 0; j < 4; ++j) acc[i][j] = (f32x4){0.f, 0.f, 0.f, 0.f};
  for (int k0 = 0; k0 < DIM; k0 += 32) {
    short8 af0 = ld8(attT + (size_t)(m0 + col) * DIM + k0 + 8 * grp);
    short8 af1 = ld8(attT + (size_t)(m0 + 16 + col) * DIM + k0 + 8 * grp);
#pragma unroll
    for (int nt = 0; nt < 4; ++nt) {
      short8 bf = ld8(wob + (size_t)(n0 + nt * 16 + col) * DIM + k0 + 8 * grp);
      acc[0][nt] = mfma_bf16(af0, bf, acc[0][nt]);
      acc[1][nt] = mfma_bf16(af1, bf, acc[1][nt]);
    }
  }
#pragma unroll
  for (int nt = 0; nt < 4; ++nt) {
    int n = n0 + nt * 16 + col;
    float bsv = bo[n];
#pragma unroll
    for (int mi = 0; mi < 2; ++mi) {
#pragma unroll
      for (int r = 0; r < 4; ++r) {
        int m = m0 + 16 * mi + 4 * grp + r;
        out[(size_t)m * DIM + n] = acc[mi][nt][r] + bsv;
      }
    }
  }
}

extern "C" void kernel_launch(void* const* d_in, const int* in_sizes, int n_in,
                              void* d_out, int out_size, void* d_ws, size_t ws_size,
                              hipStream_t stream) {
  const float* x    = (const float*)d_in[0];
  // d_in[1] = mask (causal triu, hardcoded)
  const float* ln_g = (const float*)d_in[2];
  const float* ln_b = (const float*)d_in[3];
  const float* wq   = (const float*)d_in[4];
  const float* bq   = (const float*)d_in[5];
  const float* wk   = (const float*)d_in[6];
  const float* bk   = (const float*)d_in[7];
  const float* wv   = (const float*)d_in[8];
  const float* bv   = (const float*)d_in[9];
  const float* wo   = (const float*)d_in[10];
  const float* bo   = (const float*)d_in[11];
  const float* Er   = (const float*)d_in[12];
  float* out = (float*)d_out;

  char* ws = (char*)d_ws;
  unsigned short* hn   = (unsigned short*)(ws);                    // 0..4 MiB
  unsigned short* qb   = (unsigned short*)(ws + (4u << 20));       // 4..8
  unsigned short* kb   = (unsigned short*)(ws + (8u << 20));       // 8..12
  unsigned short* vT   = (unsigned short*)(ws + (12u << 20));      // 12..16
  unsigned short* erb  = (unsigned short*)(ws + (16u << 20));      // 16..18
  unsigned short* attT = (unsigned short*)(ws + (18u << 20));      // 18..22
  unsigned short* wqb  = (unsigned short*)(ws + (22u << 20));      // 22..24
  unsigned short* wkb  = wqb + 512 * 512;
  unsigned short* wvb  = wkb + 512 * 512;
  unsigned short* wob  = wvb + 512 * 512;

  cvt_all_kernel<<<2048, 256, 0, stream>>>(wq, wk, wv, wo, Er, wqb, wkb, wvb, wob, erb);
  ln_kernel<<<1024, 256, 0, stream>>>(x, ln_g, ln_b, hn);
  qkv_kernel<<<768, 256, 0, stream>>>(hn, wqb, wkb, wvb, bq, bk, bv, qb, kb, vT);
  attn_kernel<<<512, 256, 0, stream>>>(qb, kb, vT, erb, attT);
  out_kernel<<<256, 256, 0, stream>>>(attT, wob, bo, out);
}

// Round 7
// 179.795 us; speedup vs baseline: 1.3952x; 1.3952x over previous
//
#include <hip/hip_runtime.h>

#define LSEQ 2048
#define DIM 512
#define NH 8
#define HS 64

typedef __attribute__((ext_vector_type(8))) short short8;
typedef __attribute__((ext_vector_type(4))) float f32x4;

__device__ inline unsigned short f2bf(float f) {
  union { float f; unsigned u; } a; a.f = f;
  unsigned r = a.u + 0x7FFFu + ((a.u >> 16) & 1u);
  return (unsigned short)(r >> 16);
}
__device__ inline float bf2f(unsigned short h) {
  union { unsigned u; float f; } a; a.u = ((unsigned)h) << 16;
  return a.f;
}

__device__ inline f32x4 mfma_bf16(short8 a, short8 b, f32x4 c) {
  return __builtin_amdgcn_mfma_f32_16x16x32_bf16(a, b, c, 0, 0, 0);
}

__device__ inline short8 ld8(const unsigned short* p) {
  return *reinterpret_cast<const short8*>(p);
}

// ---------------- fused fp32 -> bf16 weight/Er convert ----------------
// Er is pre-scaled by log2(e) so attention logits live in the log2 domain.
__global__ __launch_bounds__(256) void cvt_all_kernel(
    const float* __restrict__ wq, const float* __restrict__ wk,
    const float* __restrict__ wv, const float* __restrict__ wo,
    const float* __restrict__ Er,
    unsigned short* __restrict__ wqb, unsigned short* __restrict__ wkb,
    unsigned short* __restrict__ wvb, unsigned short* __restrict__ wob,
    unsigned short* __restrict__ erb) {
  int b = blockIdx.x;
  const float* src; unsigned short* dst; int off;
  float scl = 1.f;
  if (b < 256)       { src = wq; dst = wqb; off = b; }
  else if (b < 512)  { src = wk; dst = wkb; off = b - 256; }
  else if (b < 768)  { src = wv; dst = wvb; off = b - 512; }
  else if (b < 1024) { src = wo; dst = wob; off = b - 768; }
  else               { src = Er; dst = erb; off = b - 1024; scl = 1.4426950408889634f; }
  int i = (off * 256 + threadIdx.x) * 4;
  float4 v = *reinterpret_cast<const float4*>(src + i);
  unsigned lo = (unsigned)f2bf(v.x * scl) | ((unsigned)f2bf(v.y * scl) << 16);
  unsigned hi = (unsigned)f2bf(v.z * scl) | ((unsigned)f2bf(v.w * scl) << 16);
  uint2 pk; pk.x = lo; pk.y = hi;
  *reinterpret_cast<uint2*>(dst + i) = pk;
}

// ---------------- LayerNorm: one wave per row, no barriers ----------------
__global__ __launch_bounds__(256) void ln_kernel(const float* __restrict__ x,
    const float* __restrict__ g, const float* __restrict__ bta,
    unsigned short* __restrict__ hn) {
  int lane = threadIdx.x & 63, w = threadIdx.x >> 6;
  int row = blockIdx.x * 4 + w;
  const float4* xr = reinterpret_cast<const float4*>(x + (size_t)row * DIM);
  float4 a = xr[2 * lane], c = xr[2 * lane + 1];
  float s = a.x + a.y + a.z + a.w + c.x + c.y + c.z + c.w;
  float sq = a.x * a.x + a.y * a.y + a.z * a.z + a.w * a.w +
             c.x * c.x + c.y * c.y + c.z * c.z + c.w * c.w;
#pragma unroll
  for (int off = 1; off < 64; off <<= 1) {
    s += __shfl_xor(s, off);
    sq += __shfl_xor(sq, off);
  }
  float mu = s * (1.f / DIM);
  float var = sq * (1.f / DIM) - mu * mu;
  float rstd = rsqrtf(var + 1e-5f);
  float4 g0 = reinterpret_cast<const float4*>(g)[2 * lane];
  float4 g1 = reinterpret_cast<const float4*>(g)[2 * lane + 1];
  float4 b0 = reinterpret_cast<const float4*>(bta)[2 * lane];
  float4 b1 = reinterpret_cast<const float4*>(bta)[2 * lane + 1];
  uint4 o;
  o.x = (unsigned)f2bf((a.x - mu) * rstd * g0.x + b0.x) |
        ((unsigned)f2bf((a.y - mu) * rstd * g0.y + b0.y) << 16);
  o.y = (unsigned)f2bf((a.z - mu) * rstd * g0.z + b0.z) |
        ((unsigned)f2bf((a.w - mu) * rstd * g0.w + b0.w) << 16);
  o.z = (unsigned)f2bf((c.x - mu) * rstd * g1.x + b1.x) |
        ((unsigned)f2bf((c.y - mu) * rstd * g1.y + b1.y) << 16);
  o.w = (unsigned)f2bf((c.z - mu) * rstd * g1.z + b1.z) |
        ((unsigned)f2bf((c.w - mu) * rstd * g1.w + b1.w) << 16);
  reinterpret_cast<uint4*>(hn)[(size_t)row * 64 + lane] = o;
}

// ---------------- QKV projections: 32x64 tile per wave ----------------
// K is pre-scaled by 0.125*log2(e) so QK^T MFMA output is a log2-domain logit.
__global__ __launch_bounds__(256) void qkv_kernel(const unsigned short* __restrict__ hn,
    const unsigned short* __restrict__ wqb, const unsigned short* __restrict__ wkb,
    const unsigned short* __restrict__ wvb,
    const float* __restrict__ bq, const float* __restrict__ bk, const float* __restrict__ bv,
    unsigned short* __restrict__ qo, unsigned short* __restrict__ ko,
    unsigned short* __restrict__ vT) {
  int lane = threadIdx.x & 63, widx = threadIdx.x >> 6;
  int col = lane & 15, grp = lane >> 4;
  int wgid = blockIdx.x * 4 + widx;  // 0..3071
  int mat = wgid >> 10;
  int rem = wgid & 1023;
  int m0 = (rem >> 3) * 32;
  int n0 = (rem & 7) * 64;
  const unsigned short* W = (mat == 0) ? wqb : (mat == 1) ? wkb : wvb;
  const float* bias = (mat == 0) ? bq : (mat == 1) ? bk : bv;
  float scl = (mat == 1) ? 0.18033688011112042f : 1.f;  // 0.125*log2(e)
  f32x4 acc[2][4];
#pragma unroll
  for (int i = 0; i < 2; ++i)
#pragma unroll
    for (int j = 0; j < 4; ++j) acc[i][j] = (f32x4){0.f, 0.f, 0.f, 0.f};
  for (int k0 = 0; k0 < DIM; k0 += 32) {
    short8 af0 = ld8(hn + (size_t)(m0 + col) * DIM + k0 + 8 * grp);
    short8 af1 = ld8(hn + (size_t)(m0 + 16 + col) * DIM + k0 + 8 * grp);
#pragma unroll
    for (int nt = 0; nt < 4; ++nt) {
      short8 bf = ld8(W + (size_t)(n0 + nt * 16 + col) * DIM + k0 + 8 * grp);
      acc[0][nt] = mfma_bf16(af0, bf, acc[0][nt]);
      acc[1][nt] = mfma_bf16(af1, bf, acc[1][nt]);
    }
  }
#pragma unroll
  for (int nt = 0; nt < 4; ++nt) {
    int n = n0 + nt * 16 + col;   // feature
    int hh = n >> 6, d = n & 63;
    float bsv = bias[n];
#pragma unroll
    for (int mi = 0; mi < 2; ++mi) {
#pragma unroll
      for (int r = 0; r < 4; ++r) {
        int m = m0 + 16 * mi + 4 * grp + r;   // token
        float val = (acc[mi][nt][r] + bsv) * scl;
        int b = m >> 11, l = m & (LSEQ - 1);
        unsigned short hv = f2bf(val);
        if (mat == 2)
          vT[((size_t)(b * NH + hh) * HS + d) * LSEQ + l] = hv;
        else {
          unsigned short* dst = (mat == 0) ? qo : ko;
          dst[((size_t)(b * NH + hh) * LSEQ + l) * HS + d] = hv;
        }
      }
    }
  }
}

// ---------------- flash attention with skewed rel bias, chunked ----------
// one wave per (bh, 16-row q-tile, <=256-key chunk): 9216 independent waves
// looping over up to 4 x 64-key iterations. exp2-domain softmax (K, Er
// pre-scaled). No barriers; per-wave U strip in LDS. Partials -> merge.
__global__ __launch_bounds__(256, 4) void attn_kernel(const unsigned short* __restrict__ q,
    const unsigned short* __restrict__ k, const unsigned short* __restrict__ vT,
    const unsigned short* __restrict__ erb, char* __restrict__ partials) {
  __shared__ float Uall[4][80 * 18];
  int lane = threadIdx.x & 63, widx = threadIdx.x >> 6;
  int mcol = lane & 15, grp = lane >> 4;
  float* U = Uall[widx];
  // XCD pinning: 2304 blocks; xcd = bid&7 hosts bh = xcd and xcd+8.
  int bid = blockIdx.x;
  int xcd = bid & 7, q_ = bid >> 3;        // 0..287
  int hi2 = (q_ >= 144) ? 1 : 0;
  int bh = xcd + 8 * hi2;
  int b2 = q_ - 144 * hi2;                 // 0..143
  int lu = b2 * 4 + widx;                  // 0..575
  // decode lu -> (tile, chunk): tiles [16g,16g+15] have g+1 chunks
  int g = 0;
#pragma unroll
  for (int t = 1; t < 8; ++t) if (8 * t * (t + 1) <= lu) g = t;
  int idx = lu - 8 * g * (g + 1);
  int qd = idx / (g + 1);
  int tile = 16 * g + qd;
  int chunk = idx - qd * (g + 1);
  int qi0 = tile << 4;
  int c0 = chunk << 8;
  int kend = min(c0 + 256, qi0 + 16);
  int nkb = (kend - c0 + 63) >> 6;
  int h = bh & 7;

  const unsigned short* Qb = q + (size_t)bh * LSEQ * HS;
  const unsigned short* Kb = k + (size_t)bh * LSEQ * HS;
  const unsigned short* Vb = vT + (size_t)bh * HS * LSEQ;
  const unsigned short* Eb = erb + (size_t)h * LSEQ * HS;

  short8 qf0 = ld8(Qb + (size_t)(qi0 + mcol) * HS + 8 * grp);
  short8 qf1 = ld8(Qb + (size_t)(qi0 + mcol) * HS + 32 + 8 * grp);
  f32x4 o[4];
#pragma unroll
  for (int i = 0; i < 4; ++i) o[i] = (f32x4){0.f, 0.f, 0.f, 0.f};
  float mrun = -3e38f, lsum = 0.f;

  for (int kb = 0; kb < nkb; ++kb) {
    int kj0 = c0 + (kb << 6);
    int e0 = 2032 - qi0 + kj0;
    // ---- Er + K loads ----
    short8 ef[10];
#pragma unroll
    for (int jt = 0; jt < 5; ++jt) {
      int er = min(e0 + 16 * jt + mcol, 2047);  // clamped rows feed masked cells
      ef[2 * jt]     = ld8(Eb + (size_t)er * HS + 8 * grp);
      ef[2 * jt + 1] = ld8(Eb + (size_t)er * HS + 32 + 8 * grp);
    }
    short8 kf[8];
#pragma unroll
    for (int t = 0; t < 4; ++t) {
      kf[2 * t]     = ld8(Kb + (size_t)(kj0 + 16 * t + mcol) * HS + 8 * grp);
      kf[2 * t + 1] = ld8(Kb + (size_t)(kj0 + 16 * t + mcol) * HS + 32 + 8 * grp);
    }
    // ---- rel-bias band U[j][m], j in [0,80) (log2 domain) ----
#pragma unroll
    for (int jt = 0; jt < 5; ++jt) {
      f32x4 uu = (f32x4){0.f, 0.f, 0.f, 0.f};
      uu = mfma_bf16(ef[2 * jt], qf0, uu);
      uu = mfma_bf16(ef[2 * jt + 1], qf1, uu);
#pragma unroll
      for (int r = 0; r < 4; ++r)
        U[(16 * jt + 4 * grp + r) * 18 + mcol] = uu[r];
    }
    // ---- scores S^T (log2 domain; K pre-scaled) ----
    f32x4 st[4];
#pragma unroll
    for (int t = 0; t < 4; ++t) {
      f32x4 a = (f32x4){0.f, 0.f, 0.f, 0.f};
      a = mfma_bf16(kf[2 * t], qf0, a);
      a = mfma_bf16(kf[2 * t + 1], qf1, a);
      st[t] = a;
    }
    // ---- V loads (deferred: needed only after softmax) ----
    short8 vf[8];
#pragma unroll
    for (int s2 = 0; s2 < 2; ++s2)
#pragma unroll
      for (int dt = 0; dt < 4; ++dt)
        vf[s2 * 4 + dt] = ld8(Vb + (size_t)(dt * 16 + mcol) * LSEQ + kj0 + 32 * s2 + 8 * grp);
    // ---- logits + causal mask + skew gather rel[n][m] = U[n-m+15][m] ----
    float lt[4][4];
    float pmax = -3e38f;
#pragma unroll
    for (int t = 0; t < 4; ++t) {
#pragma unroll
      for (int r = 0; r < 4; ++r) {
        int n = 16 * t + 4 * grp + r;
        float val = st[t][r] + U[(n - mcol + 15) * 18 + mcol];
        if (kj0 + n > qi0 + mcol) val = -3e38f;
        lt[t][r] = val;
        pmax = fmaxf(pmax, val);
      }
    }
    pmax = fmaxf(pmax, __shfl_xor(pmax, 16));
    pmax = fmaxf(pmax, __shfl_xor(pmax, 32));
    // exact defer-rescale: only rescale when some row's max grew
    if (!__all(pmax <= mrun)) {
      float mnew = fmaxf(mrun, pmax);
      float alpha = exp2f(mrun - mnew);
      lsum *= alpha;
#pragma unroll
      for (int i2 = 0; i2 < 4; ++i2) o[i2] *= alpha;
      mrun = mnew;
    }
    float psum = 0.f;
#pragma unroll
    for (int t = 0; t < 4; ++t) {
#pragma unroll
      for (int r = 0; r < 4; ++r) {
        lt[t][r] = exp2f(lt[t][r] - mrun);
        psum += lt[t][r];
      }
    }
    psum += __shfl_xor(psum, 16);
    psum += __shfl_xor(psum, 32);
    lsum += psum;
    // ---- pack P and redistribute to B-fragment via shuffles ----
    unsigned w0[4], w1[4];
#pragma unroll
    for (int t = 0; t < 4; ++t) {
      w0[t] = (unsigned)f2bf(lt[t][0]) | ((unsigned)f2bf(lt[t][1]) << 16);
      w1[t] = (unsigned)f2bf(lt[t][2]) | ((unsigned)f2bf(lt[t][3]) << 16);
    }
    int srcA = mcol | ((grp & 1) << 5);
    int srcB = srcA + 16;
    bool hi = (grp >= 2);
#pragma unroll
    for (int s2 = 0; s2 < 2; ++s2) {
      unsigned y0a = (unsigned)__shfl((int)w0[2 * s2], srcA);
      unsigned y0b = (unsigned)__shfl((int)w0[2 * s2 + 1], srcA);
      unsigned y1a = (unsigned)__shfl((int)w1[2 * s2], srcA);
      unsigned y1b = (unsigned)__shfl((int)w1[2 * s2 + 1], srcA);
      unsigned y2a = (unsigned)__shfl((int)w0[2 * s2], srcB);
      unsigned y2b = (unsigned)__shfl((int)w0[2 * s2 + 1], srcB);
      unsigned y3a = (unsigned)__shfl((int)w1[2 * s2], srcB);
      unsigned y3b = (unsigned)__shfl((int)w1[2 * s2 + 1], srcB);
      union { unsigned u4[4]; short8 s8; } pu;
      pu.u4[0] = hi ? y0b : y0a;
      pu.u4[1] = hi ? y1b : y1a;
      pu.u4[2] = hi ? y2b : y2a;
      pu.u4[3] = hi ? y3b : y3a;
#pragma unroll
      for (int dt = 0; dt < 4; ++dt)
        o[dt] = mfma_bf16(vf[s2 * 4 + dt], pu.s8, o[dt]);
    }
  }
  // ---- write raw partial: O (16x64 bf16), m[16] (log2 domain), l[16] ----
  int u = bh * 576 + lu;
  char* pb = partials + (size_t)u * 2176;
  unsigned* Ob = (unsigned*)pb;
#pragma unroll
  for (int dt = 0; dt < 4; ++dt) {
    unsigned a = (unsigned)f2bf(o[dt][0]) | ((unsigned)f2bf(o[dt][1]) << 16);
    unsigned b3 = (unsigned)f2bf(o[dt][2]) | ((unsigned)f2bf(o[dt][3]) << 16);
    Ob[mcol * 32 + dt * 8 + grp * 2] = a;
    Ob[mcol * 32 + dt * 8 + grp * 2 + 1] = b3;
  }
  if (grp == 0) {
    ((float*)(pb + 2048))[mcol] = mrun;
    ((float*)(pb + 2112))[mcol] = lsum;
  }
}

// ---------------- merge partials -> attT (exp2 domain) ----------------
__global__ __launch_bounds__(256) void merge_kernel(const char* __restrict__ partials,
    unsigned short* __restrict__ attT) {
  int lane = threadIdx.x & 63, widx = threadIdx.x >> 6;
  // XCD pinning to match attn's partial placement
  int bid = blockIdx.x;                // 0..511
  int xcd = bid & 7, q_ = bid >> 3;    // 0..63
  int hi2 = (q_ >= 32) ? 1 : 0;
  int bh = xcd + 8 * hi2;
  int i = (q_ - 32 * hi2) * 4 + widx;  // 0..127 row-tile
  int g = i >> 4;                      // chunk-count group
  int base_u = bh * 576 + 8 * g * (g + 1) + (i & 15) * (g + 1);
  int nch = g + 1;
  int row = lane >> 2, d0 = (lane & 3) << 4;
  float M = -3e38f;
  for (int c = 0; c < nch; ++c) {
    const char* pb = partials + (size_t)(base_u + c) * 2176;
    M = fmaxf(M, ((const float*)(pb + 2048))[row]);
  }
  float acc[16];
#pragma unroll
  for (int j = 0; j < 16; ++j) acc[j] = 0.f;
  float lsum = 0.f;
  for (int c = 0; c < nch; ++c) {
    const char* pb = partials + (size_t)(base_u + c) * 2176;
    float mc = ((const float*)(pb + 2048))[row];
    float lc = ((const float*)(pb + 2112))[row];
    float s = exp2f(mc - M);
    lsum += s * lc;
    short8 v0 = *reinterpret_cast<const short8*>(pb + row * 128 + d0 * 2);
    short8 v1 = *reinterpret_cast<const short8*>(pb + row * 128 + d0 * 2 + 16);
#pragma unroll
    for (int j = 0; j < 8; ++j) {
      acc[j]     += s * bf2f((unsigned short)v0[j]);
      acc[8 + j] += s * bf2f((unsigned short)v1[j]);
    }
  }
  float inv = 1.f / lsum;
  int b = bh >> 3, h = bh & 7;
  unsigned short* dst = attT + ((size_t)(b * LSEQ) + i * 16 + row) * DIM + h * HS + d0;
  union { unsigned short us[16]; short8 s8[2]; } ou;
#pragma unroll
  for (int j = 0; j < 16; ++j) ou.us[j] = f2bf(acc[j] * inv);
  *reinterpret_cast<short8*>(dst) = ou.s8[0];
  *reinterpret_cast<short8*>(dst + 8) = ou.s8[1];
}

// ---------------- output projection: 32x64 tile per wave -> fp32 ----------
__global__ __launch_bounds__(256) void out_kernel(const unsigned short* __restrict__ attT,
    const unsigned short* __restrict__ wob, const float* __restrict__ bo,
    float* __restrict__ out) {
  int lane = threadIdx.x & 63, widx = threadIdx.x >> 6;
  int col = lane & 15, grp = lane >> 4;
  int wgid = blockIdx.x * 4 + widx;  // 0..1023
  int m0 = (wgid >> 3) * 32;
  int n0 = (wgid & 7) * 64;
  f32x4 acc[2][4];
#pragma unroll
  for (int i = 0; i < 2; ++i)
#pragma unroll
    for (int j = 0; j < 4; ++j) acc[i][j] = (f32x4){0.f, 0.f, 0.f, 0.f};
  for (int k0 = 0; k0 < DIM; k0 += 32) {
    short8 af0 = ld8(attT + (size_t)(m0 + col) * DIM + k0 + 8 * grp);
    short8 af1 = ld8(attT + (size_t)(m0 + 16 + col) * DIM + k0 + 8 * grp);
#pragma unroll
    for (int nt = 0; nt < 4; ++nt) {
      short8 bf = ld8(wob + (size_t)(n0 + nt * 16 + col) * DIM + k0 + 8 * grp);
      acc[0][nt] = mfma_bf16(af0, bf, acc[0][nt]);
      acc[1][nt] = mfma_bf16(af1, bf, acc[1][nt]);
    }
  }
#pragma unroll
  for (int nt = 0; nt < 4; ++nt) {
    int n = n0 + nt * 16 + col;
    float bsv = bo[n];
#pragma unroll
    for (int mi = 0; mi < 2; ++mi) {
#pragma unroll
      for (int r = 0; r < 4; ++r) {
        int m = m0 + 16 * mi + 4 * grp + r;
        out[(size_t)m * DIM + n] = acc[mi][nt][r] + bsv;
      }
    }
  }
}

extern "C" void kernel_launch(void* const* d_in, const int* in_sizes, int n_in,
                              void* d_out, int out_size, void* d_ws, size_t ws_size,
                              hipStream_t stream) {
  const float* x    = (const float*)d_in[0];
  // d_in[1] = mask (causal triu, hardcoded)
  const float* ln_g = (const float*)d_in[2];
  const float* ln_b = (const float*)d_in[3];
  const float* wq   = (const float*)d_in[4];
  const float* bq   = (const float*)d_in[5];
  const float* wk   = (const float*)d_in[6];
  const float* bk   = (const float*)d_in[7];
  const float* wv   = (const float*)d_in[8];
  const float* bv   = (const float*)d_in[9];
  const float* wo   = (const float*)d_in[10];
  const float* bo   = (const float*)d_in[11];
  const float* Er   = (const float*)d_in[12];
  float* out = (float*)d_out;

  char* ws = (char*)d_ws;
  unsigned short* hn   = (unsigned short*)(ws);                    // 0..4 MiB
  unsigned short* qb   = (unsigned short*)(ws + (4u << 20));       // 4..8
  unsigned short* kb   = (unsigned short*)(ws + (8u << 20));       // 8..12
  unsigned short* vT   = (unsigned short*)(ws + (12u << 20));      // 12..16
  unsigned short* erb  = (unsigned short*)(ws + (16u << 20));      // 16..18
  unsigned short* attT = (unsigned short*)(ws + (18u << 20));      // 18..22
  unsigned short* wqb  = (unsigned short*)(ws + (22u << 20));      // 22..24
  unsigned short* wkb  = wqb + 512 * 512;
  unsigned short* wvb  = wkb + 512 * 512;
  unsigned short* wob  = wvb + 512 * 512;
  char* partials       = ws + (24u << 20);                         // 24..~44.1 MiB

  cvt_all_kernel<<<2048, 256, 0, stream>>>(wq, wk, wv, wo, Er, wqb, wkb, wvb, wob, erb);
  ln_kernel<<<1024, 256, 0, stream>>>(x, ln_g, ln_b, hn);
  qkv_kernel<<<768, 256, 0, stream>>>(hn, wqb, wkb, wvb, bq, bk, bv, qb, kb, vT);
  attn_kernel<<<2304, 256, 0, stream>>>(qb, kb, vT, erb, partials);
  merge_kernel<<<512, 256, 0, stream>>>(partials, attT);
  out_kernel<<<256, 256, 0, stream>>>(attT, wob, bo, out);
}